// Round 5
// baseline (270.151 us; speedup 1.0000x reference)
//
#include <hip/hip_runtime.h>
#include <hip/hip_bf16.h>

#define B_ 4
#define S_ 1024
#define E_ 1024
#define H_ 16
#define D_ 64

typedef __attribute__((ext_vector_type(8))) short short8;
typedef __attribute__((ext_vector_type(4))) float f32x4;

static __device__ __forceinline__ unsigned short f2bf(float x) {
  unsigned int u = __float_as_uint(x);
  unsigned int r = u + 0x7fffu + ((u >> 16) & 1u);  // round-to-nearest-even
  return (unsigned short)(r >> 16);
}
static __device__ __forceinline__ float bf2f(unsigned short b) {
  return __uint_as_float((unsigned int)b << 16);
}

#define GL2LDS16(g, l)                                                            \
  __builtin_amdgcn_global_load_lds(                                               \
      (const __attribute__((address_space(1))) unsigned int*)(g),                 \
      (__attribute__((address_space(3))) unsigned int*)(l), 16, 0, 0)

// combined scale: (1/sqrt(D)) * log2(e) applied in-register to the MFMA score,
// so exp() is a single v_exp_f32 (2^x). Q/K stored UNSCALED (v9 numerics).
#define QSCALE 0.18033688011112042f
#define SCLAMP 115.41560327111707f  // 80 * log2(e), matches old fminf(s,80) clamp

// 16-lane sum via DPP (no LDS pipe): xor1, xor2, half-mirror, row-mirror.
static __device__ __forceinline__ float dpp_red16(float v) {
  v += __int_as_float(__builtin_amdgcn_update_dpp(0, __float_as_int(v), 0xB1, 0xF, 0xF, true));   // quad_perm [1,0,3,2]
  v += __int_as_float(__builtin_amdgcn_update_dpp(0, __float_as_int(v), 0x4E, 0xF, 0xF, true));   // quad_perm [2,3,0,1]
  v += __int_as_float(__builtin_amdgcn_update_dpp(0, __float_as_int(v), 0x141, 0xF, 0xF, true));  // row_half_mirror
  v += __int_as_float(__builtin_amdgcn_update_dpp(0, __float_as_int(v), 0x140, 0xF, 0xF, true));  // row_mirror
  return v;
}

// ---------- fused preprocessing: mask|mask^T, x->bf16, W->Wt bf16 ----------
// blocks 0..4095: mask_sym; 4096..6143: cvt_x; 6144..8191: wt transpose
__global__ __launch_bounds__(256) void prep_kernel(const int* __restrict__ mask,
                                                   const float* __restrict__ x,
                                                   const float* __restrict__ Wq,
                                                   const float* __restrict__ Wk,
                                                   unsigned char* __restrict__ msym,
                                                   unsigned short* __restrict__ xbf,
                                                   unsigned short* __restrict__ Wt) {
  __shared__ __align__(16) char u_lds[32 * 33 * 4];
  const int blk = blockIdx.x;
  const int tid = threadIdx.x;
  if (blk < 4096) {
    int (*T)[33] = (int(*)[33])u_lds;
    const int b = blk >> 10;
    const int rest = blk & 1023;
    const int i0 = (rest >> 5) << 5;
    const int j0 = (rest & 31) << 5;
    const int ii = tid >> 3;
    const int jj4 = (tid & 7) << 2;
    const size_t bO = (size_t)b * S_ * S_;
    const int4 m2 = *(const int4*)&mask[bO + (size_t)(j0 + ii) * S_ + i0 + jj4];
    T[ii][jj4 + 0] = m2.x; T[ii][jj4 + 1] = m2.y; T[ii][jj4 + 2] = m2.z; T[ii][jj4 + 3] = m2.w;
    __syncthreads();
    const int4 m1 = *(const int4*)&mask[bO + (size_t)(i0 + ii) * S_ + j0 + jj4];
    uchar4 o;
    o.x = ((m1.x != 0) || (T[jj4 + 0][ii] != 0)) ? 1 : 0;
    o.y = ((m1.y != 0) || (T[jj4 + 1][ii] != 0)) ? 1 : 0;
    o.z = ((m1.z != 0) || (T[jj4 + 2][ii] != 0)) ? 1 : 0;
    o.w = ((m1.w != 0) || (T[jj4 + 3][ii] != 0)) ? 1 : 0;
    *(uchar4*)&msym[bO + (size_t)(i0 + ii) * S_ + j0 + jj4] = o;
  } else if (blk < 6144) {
    const size_t i = ((size_t)(blk - 4096) * 256 + tid) * 8;
    const float4 a = *(const float4*)(x + i);
    const float4 b = *(const float4*)(x + i + 4);
    const ushort4 p0 = {f2bf(a.x), f2bf(a.y), f2bf(a.z), f2bf(a.w)};
    const ushort4 p1 = {f2bf(b.x), f2bf(b.y), f2bf(b.z), f2bf(b.w)};
    *(ushort4*)(xbf + i) = p0;
    *(ushort4*)(xbf + i + 4) = p1;
  } else {
    unsigned short (*T2)[36] = (unsigned short(*)[36])u_lds;
    const int wblk = blk - 6144;           // 2 * 32 * 32
    const int mat = wblk >> 10;
    const int kt = (wblk >> 5) & 31, ntb = wblk & 31;
    const float* W = mat ? Wk : Wq;
    const int r = tid >> 3, c4 = (tid & 7) << 2;
    const float4 v = *(const float4*)&W[(size_t)(kt * 32 + r) * 1024 + ntb * 32 + c4];
    T2[r][c4 + 0] = f2bf(v.x); T2[r][c4 + 1] = f2bf(v.y);
    T2[r][c4 + 2] = f2bf(v.z); T2[r][c4 + 3] = f2bf(v.w);
    __syncthreads();
    const ushort4 o = {T2[c4 + 0][r], T2[c4 + 1][r], T2[c4 + 2][r], T2[c4 + 3][r]};
    *(ushort4*)&Wt[(size_t)(mat * 1024 + ntb * 32 + r) * 1024 + kt * 32 + c4] = o;
  }
}

// ------- bf16 MFMA GEMM, BK=64: P[4096][nstride] = xbf[4096][1024] @ Wt^T --------
__global__ __launch_bounds__(256) void gemm_mfma_kernel(const unsigned short* __restrict__ Abf,
                                                        const unsigned short* __restrict__ Wt,
                                                        unsigned short* __restrict__ P,
                                                        int nstride) {
  __shared__ __align__(16) unsigned short As[128 * 64];  // 16 KB, [m][k]
  __shared__ __align__(16) unsigned short Bs[128 * 64];  // 16 KB, [n][k]
  const int tid = threadIdx.x;
  const int m0 = (blockIdx.x & 31) << 7;
  const int n0 = (blockIdx.x >> 5) << 7;
  const int wave = tid >> 6, lane = tid & 63;
  const int ln15 = lane & 15, rg = lane >> 4;
  const int wm = (wave & 1) << 6;
  const int wn = (wave >> 1) << 6;
  const int sr = tid >> 3;
  const int sc = (tid & 7) << 3;
  const unsigned short* gA = Abf + (size_t)(m0 + sr) * 1024 + sc;
  const unsigned short* gB = Wt + (size_t)(n0 + sr) * 1024 + sc;
  unsigned short* lA = As + tid * 8;
  unsigned short* lB = Bs + tid * 8;
  f32x4 acc[4][4];
#pragma unroll
  for (int i = 0; i < 4; ++i)
#pragma unroll
    for (int j = 0; j < 4; ++j) acc[i][j] = (f32x4){0.0f, 0.0f, 0.0f, 0.0f};

  const unsigned short* pa = As + (wm + ln15) * 64 + rg * 8;
  const unsigned short* pb = Bs + (wn + ln15) * 64 + rg * 8;
  for (int k0 = 0; k0 < E_; k0 += 64) {
#pragma unroll
    for (int j = 0; j < 4; ++j) {
      GL2LDS16(gA + k0 + (size_t)(j * 32) * 1024, lA + j * 2048);
      GL2LDS16(gB + k0 + (size_t)(j * 32) * 1024, lB + j * 2048);
    }
    __syncthreads();
#pragma unroll
    for (int kk = 0; kk < 2; ++kk) {
      short8 af[4], bfr[4];
#pragma unroll
      for (int i = 0; i < 4; ++i) af[i] = *(const short8*)(pa + i * 16 * 64 + kk * 32);
#pragma unroll
      for (int j = 0; j < 4; ++j) bfr[j] = *(const short8*)(pb + j * 16 * 64 + kk * 32);
#pragma unroll
      for (int i = 0; i < 4; ++i)
#pragma unroll
        for (int j = 0; j < 4; ++j)
          acc[i][j] = __builtin_amdgcn_mfma_f32_16x16x32_bf16(af[i], bfr[j], acc[i][j], 0, 0, 0);
    }
    __syncthreads();
  }
#pragma unroll
  for (int i = 0; i < 4; ++i)
#pragma unroll
    for (int j = 0; j < 4; ++j)
#pragma unroll
      for (int r = 0; r < 4; ++r) {
        const int row = m0 + wm + i * 16 + rg * 4 + r;
        const int col = n0 + wn + j * 16 + ln15;
        P[(size_t)row * nstride + col] = f2bf(acc[i][j][r]);
      }
}

// ---- bias+LN+ReLU from bf16 P; emit bf16 head-major [b*16+h][s][d] ----
__device__ __forceinline__ void ln_body(const unsigned short* p, const float* bias,
                                        const float* gamma, const float* beta,
                                        unsigned short* obf, int b, int s, int tid) {
  const ushort4 pv = *(const ushort4*)(p + tid * 4);
  float4 v = {bf2f(pv.x), bf2f(pv.y), bf2f(pv.z), bf2f(pv.w)};
  const float4 bb = ((const float4*)bias)[tid];
  v.x += bb.x; v.y += bb.y; v.z += bb.z; v.w += bb.w;
  float sum = v.x + v.y + v.z + v.w;
  float s2 = v.x * v.x + v.y * v.y + v.z * v.z + v.w * v.w;
#pragma unroll
  for (int off = 32; off >= 1; off >>= 1) {
    sum += __shfl_xor(sum, off);
    s2 += __shfl_xor(s2, off);
  }
  __shared__ float red[2][4];
  const int wave = tid >> 6, lane = tid & 63;
  if (lane == 0) { red[0][wave] = sum; red[1][wave] = s2; }
  __syncthreads();
  sum = red[0][0] + red[0][1] + red[0][2] + red[0][3];
  s2 = red[1][0] + red[1][1] + red[1][2] + red[1][3];
  const float mu = sum * (1.0f / E_);
  const float var = s2 * (1.0f / E_) - mu * mu;
  const float r = rsqrtf(var + 1e-5f);
  const float4 g = ((const float4*)gamma)[tid];
  const float4 bt = ((const float4*)beta)[tid];
  const float o0 = fmaxf((v.x - mu) * r * g.x + bt.x, 0.0f);
  const float o1 = fmaxf((v.y - mu) * r * g.y + bt.y, 0.0f);
  const float o2 = fmaxf((v.z - mu) * r * g.z + bt.z, 0.0f);
  const float o3 = fmaxf((v.w - mu) * r * g.w + bt.w, 0.0f);
  const int h = tid >> 4;
  const int d = (tid & 15) << 2;
  const ushort4 ob = {f2bf(o0), f2bf(o1), f2bf(o2), f2bf(o3)};
  *(ushort4*)&obf[((size_t)(b * H_ + h) * S_ + s) * D_ + d] = ob;
}

__global__ __launch_bounds__(256) void ln_relu_bf_kernel(const unsigned short* __restrict__ P,
                                                         int rowstride, int coloff,
                                                         const float* __restrict__ bias,
                                                         const float* __restrict__ gamma,
                                                         const float* __restrict__ beta,
                                                         unsigned short* __restrict__ obf) {
  const int row = blockIdx.x;
  ln_body(P + (size_t)row * rowstride + coloff, bias, gamma, beta, obf,
          row >> 10, row & 1023, threadIdx.x);
}

// fused both-LN launch (40MB path): blocks 0..4095 -> Q, 4096..8191 -> K
__global__ __launch_bounds__(256) void ln2_kernel(const unsigned short* __restrict__ P2,
                                                  const float* __restrict__ bq,
                                                  const float* __restrict__ gq,
                                                  const float* __restrict__ bqn,
                                                  const float* __restrict__ bk,
                                                  const float* __restrict__ gk,
                                                  const float* __restrict__ bkn,
                                                  unsigned short* __restrict__ Qbf,
                                                  unsigned short* __restrict__ Kbf) {
  const int blk = blockIdx.x;
  const int sel = blk >> 12;
  const int row = blk & 4095;
  ln_body(P2 + (size_t)row * 2048 + sel * 1024,
          sel ? bk : bq, sel ? gk : gq, sel ? bkn : bqn,
          sel ? Kbf : Qbf, row >> 10, row & 1023, threadIdx.x);
}

// ======= attention v14: direct global K loads + 2-bank register prefetch =======
// v13 post-mortem: direct loads with no lookahead exposed L2 latency serially
// (VGPR_Count=44 showed the compiler used tiny load windows; ~10.9k stall
// cyc/head). v14 keeps the no-LDS-staging structure (K has zero intra-block
// reuse) but restores v12's one-step lookahead IN REGISTERS (T14 issue-early/
// consume-late): two named banks of 10 fragments (2 Q + 8 K, 40 VGPR each),
// head loop unrolled 2x: LOAD(y,h+1); COMP(x,h); LOAD(x,h+2); COMP(y,h+1).
// Loads are issued one full head-compute (~1000 cy) before first use.
// All names are plain variables (no runtime-indexed arrays -> no scratch).
// Softmax/l-exchange identical to verified v12/v13 (exp2 domain, mf
// multipliers, DPP mirrors, parity'd padded l_lds, 1 barrier/head).
__global__ __launch_bounds__(1024, 4) void attn14_kernel(const unsigned short* __restrict__ Qbf,
                                                         const unsigned short* __restrict__ Kbf,
                                                         const unsigned char* __restrict__ msym,
                                                         float* __restrict__ out) {
  __shared__ __align__(16) float l_lds[2][16][20];          // [par][wave][q, pad 20] 2.5 KB
  const int tid = threadIdx.x;
  const int wave = tid >> 6, lane = tid & 63;
  const int ln15 = lane & 15, rg = lane >> 4;
  const int b = blockIdx.x & 3;                 // XCD swizzle: K[b] L2-resident
  const int q0 = (blockIdx.x >> 2) << 4;
  const unsigned short* Kb = Kbf + (size_t)b * H_ * S_ * D_;
  const unsigned short* Qb = Qbf + (size_t)b * H_ * S_ * D_;

  // mask bits: bit(hf*8 + jt*4 + r) = msym[q0+rg*4+r][hf*512 + wave*32 + jt*16 + ln15]
  unsigned int mbits = 0;
#pragma unroll
  for (int hf = 0; hf < 2; ++hf)
#pragma unroll
    for (int jt = 0; jt < 2; ++jt)
#pragma unroll
      for (int r = 0; r < 4; ++r)
        mbits |= (msym[((size_t)b * S_ + q0 + rg * 4 + r) * S_ + hf * 512 + wave * 32 + jt * 16 + ln15]
                      ? 1u : 0u) << (hf * 8 + jt * 4 + r);
  // heads share the mask: expand once to float multipliers. Clamp keeps exp2
  // finite, so 0.0f * finite = +0.0f exactly.
  float mf[2][2][4];
#pragma unroll
  for (int hf = 0; hf < 2; ++hf)
#pragma unroll
    for (int jt = 0; jt < 2; ++jt)
#pragma unroll
      for (int r = 0; r < 4; ++r)
        mf[hf][jt][r] = ((mbits >> (hf * 8 + jt * 4 + r)) & 1u) ? 0.0f : 1.0f;

  // per-lane fragment bases (shorts): key = wave*32 + ln15 (+ jt*16 via imm,
  // + hf*512 via kb1), d-chunk = rg*8 (+32 shorts for b1 via imm).
  const unsigned short* kb0 = Kb + (size_t)(wave * 32 + ln15) * D_ + rg * 8;
  const unsigned short* kb1 = kb0 + (size_t)512 * D_;
  const unsigned short* qp = Qb + (size_t)(q0 + ln15) * D_ + rg * 8;
  const size_t HD = (size_t)S_ * D_;  // one head stride in shorts

  float o[2][2][4] = {};
  float ef[2][2][4];
  float la[4];

// issue the 10 loads for the head the pointers currently aim at, then advance
#define LOADH(A0, A1, C00A, C00B, C01A, C01B, C10A, C10B, C11A, C11B)  \
  {                                                                    \
    A0 = *(const short8*)qp;                                           \
    A1 = *(const short8*)(qp + 32);                                    \
    C00A = *(const short8*)(kb0);                                      \
    C00B = *(const short8*)(kb0 + 32);                                 \
    C01A = *(const short8*)(kb0 + 1024);                               \
    C01B = *(const short8*)(kb0 + 1056);                               \
    C10A = *(const short8*)(kb1);                                      \
    C10B = *(const short8*)(kb1 + 32);                                 \
    C11A = *(const short8*)(kb1 + 1024);                               \
    C11B = *(const short8*)(kb1 + 1056);                               \
    qp += HD; kb0 += HD; kb1 += HD;                                    \
  }

// one (hf,jt) quadrant: 2 MFMA + exp2 + mask-mult + la accumulate
#define QKQ(HF, JT, A0, A1, B0, B1)                                    \
  {                                                                    \
    f32x4 cc = {0.0f, 0.0f, 0.0f, 0.0f};                               \
    cc = __builtin_amdgcn_mfma_f32_16x16x32_bf16(A0, B0, cc, 0, 0, 0); \
    cc = __builtin_amdgcn_mfma_f32_16x16x32_bf16(A1, B1, cc, 0, 0, 0); \
    _Pragma("unroll")                                                  \
    for (int r = 0; r < 4; ++r) {                                      \
      const float sv = fminf(cc[r] * QSCALE, SCLAMP);                  \
      const float ev = __builtin_amdgcn_exp2f(sv) * mf[HF][JT][r];     \
      ef[HF][JT][r] = ev;                                              \
      la[r] += ev;                                                     \
    }                                                                  \
  }

// full head compute from one bank; PAR = head & 1 selects l_lds buffer
#define COMPH(PAR, A0, A1, C00A, C00B, C01A, C01B, C10A, C10B, C11A, C11B) \
  {                                                                        \
    la[0] = la[1] = la[2] = la[3] = 0.0f;                                  \
    QKQ(0, 0, A0, A1, C00A, C00B)                                          \
    QKQ(0, 1, A0, A1, C01A, C01B)                                          \
    QKQ(1, 0, A0, A1, C10A, C10B)                                          \
    QKQ(1, 1, A0, A1, C11A, C11B)                                          \
    _Pragma("unroll")                                                      \
    for (int r = 0; r < 4; ++r) la[r] = dpp_red16(la[r]);                  \
    if (ln15 == 0)                                                         \
      *(f32x4*)&l_lds[PAR][wave][rg * 4] = (f32x4){la[0], la[1], la[2], la[3]}; \
    __syncthreads(); /* ONE barrier per head: l exchange only */           \
    const f32x4 pw = *(const f32x4*)&l_lds[PAR][ln15][rg * 4];             \
    _Pragma("unroll")                                                      \
    for (int r = 0; r < 4; ++r) {                                          \
      const float li = __builtin_amdgcn_rcpf(dpp_red16(pw[r]));            \
      _Pragma("unroll")                                                    \
      for (int hf = 0; hf < 2; ++hf)                                       \
        _Pragma("unroll")                                                  \
        for (int jt = 0; jt < 2; ++jt) o[hf][jt][r] += ef[hf][jt][r] * li; \
    }                                                                      \
  }

  short8 xa0, xa1, xk0, xk1, xk2, xk3, xk4, xk5, xk6, xk7;  // bank X
  short8 ya0, ya1, yk0, yk1, yk2, yk3, yk4, yk5, yk6, yk7;  // bank Y

  LOADH(xa0, xa1, xk0, xk1, xk2, xk3, xk4, xk5, xk6, xk7);  // head 0
#pragma unroll 1
  for (int hh = 0; hh < 8; ++hh) {
    LOADH(ya0, ya1, yk0, yk1, yk2, yk3, yk4, yk5, yk6, yk7);  // head 2hh+1
    COMPH(0, xa0, xa1, xk0, xk1, xk2, xk3, xk4, xk5, xk6, xk7);
    if (hh < 7)
      LOADH(xa0, xa1, xk0, xk1, xk2, xk3, xk4, xk5, xk6, xk7);  // head 2hh+2
    COMPH(1, ya0, ya1, yk0, yk1, yk2, yk3, yk4, yk5, yk6, yk7);
  }
#undef LOADH
#undef QKQ
#undef COMPH
  // direct stores: 64 B contiguous per (hf,jt,r) across the 16 key-lanes;
  // 1/16 head-mean folded in here.
#pragma unroll
  for (int hf = 0; hf < 2; ++hf)
#pragma unroll
    for (int jt = 0; jt < 2; ++jt)
#pragma unroll
      for (int r = 0; r < 4; ++r)
        out[((size_t)b * S_ + q0 + rg * 4 + r) * S_ + hf * 512 + wave * 32 + jt * 16 + ln15] =
            o[hf][jt][r] * 0.0625f;
}

extern "C" void kernel_launch(void* const* d_in, const int* in_sizes, int n_in,
                              void* d_out, int out_size, void* d_ws, size_t ws_size,
                              hipStream_t stream) {
  const float* x = (const float*)d_in[0];
  const int* mask = (const int*)d_in[1];
  const float* Wq = (const float*)d_in[2];
  const float* bq = (const float*)d_in[3];
  const float* Wk = (const float*)d_in[4];
  const float* bk = (const float*)d_in[5];
  const float* gq = (const float*)d_in[6];
  const float* bq_n = (const float*)d_in[7];
  const float* gk = (const float*)d_in[8];
  const float* bk_n = (const float*)d_in[9];
  float* out = (float*)d_out;

  char* ws = (char*)d_ws;
  const size_t MB = 1024 * 1024;

  if (ws_size >= 40 * MB) {
    // fused layout (40 MB): P2 bf16 [4096][2048] @0 (16), xbf @16 (8, Kbf aliases),
    // Wt @24 (4), Qbf @28 (8), msym @36 (4)
    unsigned short* P2 = (unsigned short*)ws;
    unsigned short* xbf = (unsigned short*)(ws + 16 * MB);
    unsigned short* Kbf = (unsigned short*)(ws + 16 * MB);   // alias: xbf dead after gemm
    unsigned short* Wt = (unsigned short*)(ws + 24 * MB);
    unsigned short* Qbf = (unsigned short*)(ws + 28 * MB);
    unsigned char* msym = (unsigned char*)(ws + 36 * MB);

    prep_kernel<<<8192, 256, 0, stream>>>(mask, x, Wq, Wk, msym, xbf, Wt);
    gemm_mfma_kernel<<<512, 256, 0, stream>>>(xbf, Wt, P2, 2048);
    ln2_kernel<<<8192, 256, 0, stream>>>(P2, bq, gq, bq_n, bk, gk, bk_n, Qbf, Kbf);
    attn14_kernel<<<256, 1024, 0, stream>>>(Qbf, Kbf, msym, out);
  } else {
    // split layout (32 MB): P bf16 [4096][1024] @0 (8), xbf @8 (8, Kbf aliases),
    // Wt @16 (4), Qbf @20 (8), msym @28 (4)
    unsigned short* P = (unsigned short*)ws;
    unsigned short* xbf = (unsigned short*)(ws + 8 * MB);
    unsigned short* Kbf = (unsigned short*)(ws + 8 * MB);    // alias: xbf dead after 2nd gemm
    unsigned short* Wt = (unsigned short*)(ws + 16 * MB);
    unsigned short* Qbf = (unsigned short*)(ws + 20 * MB);
    unsigned char* msym = (unsigned char*)(ws + 28 * MB);

    prep_kernel<<<8192, 256, 0, stream>>>(mask, x, Wq, Wk, msym, xbf, Wt);
    gemm_mfma_kernel<<<256, 256, 0, stream>>>(xbf, Wt, P, 1024);
    ln_relu_bf_kernel<<<4096, 256, 0, stream>>>(P, 1024, 0, bq, gq, bq_n, Qbf);
    gemm_mfma_kernel<<<256, 256, 0, stream>>>(xbf, Wt + (size_t)1024 * 1024, P, 1024);
    ln_relu_bf_kernel<<<4096, 256, 0, stream>>>(P, 1024, 0, bk, gk, bk_n, Kbf);
    attn14_kernel<<<256, 1024, 0, stream>>>(Qbf, Kbf, msym, out);
  }
}

// Round 6
// 182.785 us; speedup vs baseline: 1.4780x; 1.4780x over previous
//
#include <hip/hip_runtime.h>
#include <hip/hip_bf16.h>

#define B_ 4
#define S_ 1024
#define E_ 1024
#define H_ 16
#define D_ 64

typedef __attribute__((ext_vector_type(8))) short short8;
typedef __attribute__((ext_vector_type(4))) float f32x4;

static __device__ __forceinline__ unsigned short f2bf(float x) {
  unsigned int u = __float_as_uint(x);
  unsigned int r = u + 0x7fffu + ((u >> 16) & 1u);  // round-to-nearest-even
  return (unsigned short)(r >> 16);
}
static __device__ __forceinline__ float bf2f(unsigned short b) {
  return __uint_as_float((unsigned int)b << 16);
}

#define GL2LDS16(g, l)                                                            \
  __builtin_amdgcn_global_load_lds(                                               \
      (const __attribute__((address_space(1))) unsigned int*)(g),                 \
      (__attribute__((address_space(3))) unsigned int*)(l), 16, 0, 0)

// gfx9 s_waitcnt imm: vmcnt[3:0]|[15:14], expcnt[6:4], lgkmcnt[11:8].
// vmcnt(4) = 0x0F74, vmcnt(0) = 0x0F70 (expcnt/lgkmcnt left free).
#define WAIT_VMCNT4() __builtin_amdgcn_s_waitcnt(0x0F74)
#define WAIT_VMCNT0() __builtin_amdgcn_s_waitcnt(0x0F70)

// Raw barrier WITHOUT the vmcnt(0) drain __syncthreads would emit.
// Legal: K staging is wave-private (no cross-wave reads of Ks), so only the
// l_lds ds ops need visibility -> lgkmcnt(0) before s_barrier. The "memory"
// clobber pins the preceding ds_write; s_barrier's side effects stop motion.
#define BARRIER_LGKM()                                      \
  do {                                                      \
    asm volatile("s_waitcnt lgkmcnt(0)" ::: "memory");      \
    __builtin_amdgcn_s_barrier();                           \
  } while (0)

// combined scale: (1/sqrt(D)) * log2(e) applied in-register to the MFMA score,
// so exp() is a single v_exp_f32 (2^x). Q/K stored UNSCALED (v9 numerics).
#define QSCALE 0.18033688011112042f
#define SCLAMP 115.41560327111707f  // 80 * log2(e), matches old fminf(s,80) clamp

// 16-lane sum via DPP (no LDS pipe): xor1, xor2, half-mirror, row-mirror.
static __device__ __forceinline__ float dpp_red16(float v) {
  v += __int_as_float(__builtin_amdgcn_update_dpp(0, __float_as_int(v), 0xB1, 0xF, 0xF, true));   // quad_perm [1,0,3,2]
  v += __int_as_float(__builtin_amdgcn_update_dpp(0, __float_as_int(v), 0x4E, 0xF, 0xF, true));   // quad_perm [2,3,0,1]
  v += __int_as_float(__builtin_amdgcn_update_dpp(0, __float_as_int(v), 0x141, 0xF, 0xF, true));  // row_half_mirror
  v += __int_as_float(__builtin_amdgcn_update_dpp(0, __float_as_int(v), 0x140, 0xF, 0xF, true));  // row_mirror
  return v;
}

// ---------- fused preprocessing: mask|mask^T, x->bf16, W->Wt bf16 ----------
// blocks 0..4095: mask_sym; 4096..6143: cvt_x; 6144..8191: wt transpose
__global__ __launch_bounds__(256) void prep_kernel(const int* __restrict__ mask,
                                                   const float* __restrict__ x,
                                                   const float* __restrict__ Wq,
                                                   const float* __restrict__ Wk,
                                                   unsigned char* __restrict__ msym,
                                                   unsigned short* __restrict__ xbf,
                                                   unsigned short* __restrict__ Wt) {
  __shared__ __align__(16) char u_lds[32 * 33 * 4];
  const int blk = blockIdx.x;
  const int tid = threadIdx.x;
  if (blk < 4096) {
    int (*T)[33] = (int(*)[33])u_lds;
    const int b = blk >> 10;
    const int rest = blk & 1023;
    const int i0 = (rest >> 5) << 5;
    const int j0 = (rest & 31) << 5;
    const int ii = tid >> 3;
    const int jj4 = (tid & 7) << 2;
    const size_t bO = (size_t)b * S_ * S_;
    const int4 m2 = *(const int4*)&mask[bO + (size_t)(j0 + ii) * S_ + i0 + jj4];
    T[ii][jj4 + 0] = m2.x; T[ii][jj4 + 1] = m2.y; T[ii][jj4 + 2] = m2.z; T[ii][jj4 + 3] = m2.w;
    __syncthreads();
    const int4 m1 = *(const int4*)&mask[bO + (size_t)(i0 + ii) * S_ + j0 + jj4];
    uchar4 o;
    o.x = ((m1.x != 0) || (T[jj4 + 0][ii] != 0)) ? 1 : 0;
    o.y = ((m1.y != 0) || (T[jj4 + 1][ii] != 0)) ? 1 : 0;
    o.z = ((m1.z != 0) || (T[jj4 + 2][ii] != 0)) ? 1 : 0;
    o.w = ((m1.w != 0) || (T[jj4 + 3][ii] != 0)) ? 1 : 0;
    *(uchar4*)&msym[bO + (size_t)(i0 + ii) * S_ + j0 + jj4] = o;
  } else if (blk < 6144) {
    const size_t i = ((size_t)(blk - 4096) * 256 + tid) * 8;
    const float4 a = *(const float4*)(x + i);
    const float4 b = *(const float4*)(x + i + 4);
    const ushort4 p0 = {f2bf(a.x), f2bf(a.y), f2bf(a.z), f2bf(a.w)};
    const ushort4 p1 = {f2bf(b.x), f2bf(b.y), f2bf(b.z), f2bf(b.w)};
    *(ushort4*)(xbf + i) = p0;
    *(ushort4*)(xbf + i + 4) = p1;
  } else {
    unsigned short (*T2)[36] = (unsigned short(*)[36])u_lds;
    const int wblk = blk - 6144;           // 2 * 32 * 32
    const int mat = wblk >> 10;
    const int kt = (wblk >> 5) & 31, ntb = wblk & 31;
    const float* W = mat ? Wk : Wq;
    const int r = tid >> 3, c4 = (tid & 7) << 2;
    const float4 v = *(const float4*)&W[(size_t)(kt * 32 + r) * 1024 + ntb * 32 + c4];
    T2[r][c4 + 0] = f2bf(v.x); T2[r][c4 + 1] = f2bf(v.y);
    T2[r][c4 + 2] = f2bf(v.z); T2[r][c4 + 3] = f2bf(v.w);
    __syncthreads();
    const ushort4 o = {T2[c4 + 0][r], T2[c4 + 1][r], T2[c4 + 2][r], T2[c4 + 3][r]};
    *(ushort4*)&Wt[(size_t)(mat * 1024 + ntb * 32 + r) * 1024 + kt * 32 + c4] = o;
  }
}

// ------- bf16 MFMA GEMM, BK=64: P[4096][nstride] = xbf[4096][1024] @ Wt^T --------
__global__ __launch_bounds__(256) void gemm_mfma_kernel(const unsigned short* __restrict__ Abf,
                                                        const unsigned short* __restrict__ Wt,
                                                        unsigned short* __restrict__ P,
                                                        int nstride) {
  __shared__ __align__(16) unsigned short As[128 * 64];  // 16 KB, [m][k]
  __shared__ __align__(16) unsigned short Bs[128 * 64];  // 16 KB, [n][k]
  const int tid = threadIdx.x;
  const int m0 = (blockIdx.x & 31) << 7;
  const int n0 = (blockIdx.x >> 5) << 7;
  const int wave = tid >> 6, lane = tid & 63;
  const int ln15 = lane & 15, rg = lane >> 4;
  const int wm = (wave & 1) << 6;
  const int wn = (wave >> 1) << 6;
  const int sr = tid >> 3;
  const int sc = (tid & 7) << 3;
  const unsigned short* gA = Abf + (size_t)(m0 + sr) * 1024 + sc;
  const unsigned short* gB = Wt + (size_t)(n0 + sr) * 1024 + sc;
  unsigned short* lA = As + tid * 8;
  unsigned short* lB = Bs + tid * 8;
  f32x4 acc[4][4];
#pragma unroll
  for (int i = 0; i < 4; ++i)
#pragma unroll
    for (int j = 0; j < 4; ++j) acc[i][j] = (f32x4){0.0f, 0.0f, 0.0f, 0.0f};

  const unsigned short* pa = As + (wm + ln15) * 64 + rg * 8;
  const unsigned short* pb = Bs + (wn + ln15) * 64 + rg * 8;
  for (int k0 = 0; k0 < E_; k0 += 64) {
#pragma unroll
    for (int j = 0; j < 4; ++j) {
      GL2LDS16(gA + k0 + (size_t)(j * 32) * 1024, lA + j * 2048);
      GL2LDS16(gB + k0 + (size_t)(j * 32) * 1024, lB + j * 2048);
    }
    __syncthreads();
#pragma unroll
    for (int kk = 0; kk < 2; ++kk) {
      short8 af[4], bfr[4];
#pragma unroll
      for (int i = 0; i < 4; ++i) af[i] = *(const short8*)(pa + i * 16 * 64 + kk * 32);
#pragma unroll
      for (int j = 0; j < 4; ++j) bfr[j] = *(const short8*)(pb + j * 16 * 64 + kk * 32);
#pragma unroll
      for (int i = 0; i < 4; ++i)
#pragma unroll
        for (int j = 0; j < 4; ++j)
          acc[i][j] = __builtin_amdgcn_mfma_f32_16x16x32_bf16(af[i], bfr[j], acc[i][j], 0, 0, 0);
    }
    __syncthreads();
  }
#pragma unroll
  for (int i = 0; i < 4; ++i)
#pragma unroll
    for (int j = 0; j < 4; ++j)
#pragma unroll
      for (int r = 0; r < 4; ++r) {
        const int row = m0 + wm + i * 16 + rg * 4 + r;
        const int col = n0 + wn + j * 16 + ln15;
        P[(size_t)row * nstride + col] = f2bf(acc[i][j][r]);
      }
}

// ---- bias+LN+ReLU from bf16 P; emit bf16 head-major [b*16+h][s][d] ----
__device__ __forceinline__ void ln_body(const unsigned short* p, const float* bias,
                                        const float* gamma, const float* beta,
                                        unsigned short* obf, int b, int s, int tid) {
  const ushort4 pv = *(const ushort4*)(p + tid * 4);
  float4 v = {bf2f(pv.x), bf2f(pv.y), bf2f(pv.z), bf2f(pv.w)};
  const float4 bb = ((const float4*)bias)[tid];
  v.x += bb.x; v.y += bb.y; v.z += bb.z; v.w += bb.w;
  float sum = v.x + v.y + v.z + v.w;
  float s2 = v.x * v.x + v.y * v.y + v.z * v.z + v.w * v.w;
#pragma unroll
  for (int off = 32; off >= 1; off >>= 1) {
    sum += __shfl_xor(sum, off);
    s2 += __shfl_xor(s2, off);
  }
  __shared__ float red[2][4];
  const int wave = tid >> 6, lane = tid & 63;
  if (lane == 0) { red[0][wave] = sum; red[1][wave] = s2; }
  __syncthreads();
  sum = red[0][0] + red[0][1] + red[0][2] + red[0][3];
  s2 = red[1][0] + red[1][1] + red[1][2] + red[1][3];
  const float mu = sum * (1.0f / E_);
  const float var = s2 * (1.0f / E_) - mu * mu;
  const float r = rsqrtf(var + 1e-5f);
  const float4 g = ((const float4*)gamma)[tid];
  const float4 bt = ((const float4*)beta)[tid];
  const float o0 = fmaxf((v.x - mu) * r * g.x + bt.x, 0.0f);
  const float o1 = fmaxf((v.y - mu) * r * g.y + bt.y, 0.0f);
  const float o2 = fmaxf((v.z - mu) * r * g.z + bt.z, 0.0f);
  const float o3 = fmaxf((v.w - mu) * r * g.w + bt.w, 0.0f);
  const int h = tid >> 4;
  const int d = (tid & 15) << 2;
  const ushort4 ob = {f2bf(o0), f2bf(o1), f2bf(o2), f2bf(o3)};
  *(ushort4*)&obf[((size_t)(b * H_ + h) * S_ + s) * D_ + d] = ob;
}

__global__ __launch_bounds__(256) void ln_relu_bf_kernel(const unsigned short* __restrict__ P,
                                                         int rowstride, int coloff,
                                                         const float* __restrict__ bias,
                                                         const float* __restrict__ gamma,
                                                         const float* __restrict__ beta,
                                                         unsigned short* __restrict__ obf) {
  const int row = blockIdx.x;
  ln_body(P + (size_t)row * rowstride + coloff, bias, gamma, beta, obf,
          row >> 10, row & 1023, threadIdx.x);
}

// fused both-LN launch (40MB path): blocks 0..4095 -> Q, 4096..8191 -> K
__global__ __launch_bounds__(256) void ln2_kernel(const unsigned short* __restrict__ P2,
                                                  const float* __restrict__ bq,
                                                  const float* __restrict__ gq,
                                                  const float* __restrict__ bqn,
                                                  const float* __restrict__ bk,
                                                  const float* __restrict__ gk,
                                                  const float* __restrict__ bkn,
                                                  unsigned short* __restrict__ Qbf,
                                                  unsigned short* __restrict__ Kbf) {
  const int blk = blockIdx.x;
  const int sel = blk >> 12;
  const int row = blk & 4095;
  ln_body(P2 + (size_t)row * 2048 + sel * 1024,
          sel ? bk : bq, sel ? gk : gq, sel ? bkn : bqn,
          sel ? Kbf : Qbf, row >> 10, row & 1023, threadIdx.x);
}

// ======= attention v15: v12 + RAW per-head barrier (no vmcnt drain) =======
// v12's hidden serializer: __syncthreads compiles to s_waitcnt vmcnt(0)
// lgkmcnt(0) + s_barrier, so every head all 16 waves drained the prefetch
// DMAs they had just issued (~500-900 cy exposed latency x 16 heads).
// K staging is WAVE-PRIVATE (no wave ever reads another wave's Ks slice),
// so cross-wave visibility of the DMA data is never needed; only the 1 KB
// l_lds exchange requires barrier semantics -> lgkmcnt(0) + raw s_barrier.
// The wave-local vmcnt(4) accounting stays exact across heads: each step
// issues one 4-op batch and leaves exactly one in flight; s==31 drains fully.
// Everything else is byte-identical to the verified v12 (exp2 domain, mf
// multipliers, DPP mirrors, parity'd padded l_lds, per-step vmcnt(4)).
__global__ __launch_bounds__(1024, 4) void attn15_kernel(const unsigned short* __restrict__ Qbf,
                                                         const unsigned short* __restrict__ Kbf,
                                                         const unsigned char* __restrict__ msym,
                                                         float* __restrict__ out) {
  __shared__ __align__(16) unsigned short Ks[2][16][2048];  // [par][wave][32 keys x 64] 128 KB
  __shared__ __align__(16) float l_lds[2][16][20];          // [par][wave][q, pad 20] 2.5 KB
  const int tid = threadIdx.x;
  const int wave = tid >> 6, lane = tid & 63;
  const int ln15 = lane & 15, rg = lane >> 4;
  const int b = blockIdx.x & 3;                 // XCD swizzle: K[b] L2-resident
  const int q0 = (blockIdx.x >> 2) << 4;
  const unsigned short* Kb = Kbf + (size_t)b * H_ * S_ * D_;
  const unsigned short* Qb = Qbf + (size_t)b * H_ * S_ * D_;

  // mask bits: bit(hf*8 + jt*4 + r) = msym[q0+rg*4+r][hf*512 + wave*32 + jt*16 + ln15]
  unsigned int mbits = 0;
#pragma unroll
  for (int hf = 0; hf < 2; ++hf)
#pragma unroll
    for (int jt = 0; jt < 2; ++jt)
#pragma unroll
      for (int r = 0; r < 4; ++r)
        mbits |= (msym[((size_t)b * S_ + q0 + rg * 4 + r) * S_ + hf * 512 + wave * 32 + jt * 16 + ln15]
                      ? 1u : 0u) << (hf * 8 + jt * 4 + r);
  // heads share the mask: expand once to float multipliers. Clamp keeps exp2
  // finite, so 0.0f * finite = +0.0f exactly (identical to the old cndmask).
  float mf[2][2][4];
#pragma unroll
  for (int hf = 0; hf < 2; ++hf)
#pragma unroll
    for (int jt = 0; jt < 2; ++jt)
#pragma unroll
      for (int r = 0; r < 4; ++r)
        mf[hf][jt][r] = ((mbits >> (hf * 8 + jt * 4 + r)) & 1u) ? 0.0f : 1.0f;

  // DMA lane mapping (shorts): key_local = i*8 + (lane>>3), phys slot = lane&7,
  // global chunk = (lane&7) ^ (lane>>3)  [XOR swizzle; i*8 doesn't affect &7]
  const int gl = ((lane >> 3) << 6) + (((lane & 7) ^ (lane >> 3)) << 3);
  const unsigned short* gwave = Kb + wave * 2048 + gl;   // + hf*32768 + h*65536 + i*512
  // prologue: DMA step 0 only; each step s<31 issues batch s+1 then vmcnt(4),
  // which drains batch s (4 newer ops were just issued). s==31 issues nothing,
  // so it must drain fully.
#pragma unroll
  for (int c = 0; c < 4; ++c) GL2LDS16(gwave + c * 512, &Ks[0][wave][c * 512]);

  const int pfrag = (rg ^ (ln15 & 7)) * 8;  // swizzled chunk offset (shorts)
  float o[2][2][4] = {};
  float ef[2][2][4];
  float la[4];

#pragma unroll 1
  for (int h = 0; h < 16; ++h) {
    // A-frags from global: same 2KB for all 16 waves -> L1 broadcast
    const unsigned short* qrow = Qb + ((size_t)h * S_ + q0 + ln15) * D_ + rg * 8;
    const short8 a0 = *(const short8*)qrow;
    const short8 a1 = *(const short8*)(qrow + 32);
    la[0] = la[1] = la[2] = la[3] = 0.0f;
#pragma unroll
    for (int hf = 0; hf < 2; ++hf) {
      const int s = h * 2 + hf;
      if (s < 31) {
        const int s1 = s + 1;
        const unsigned short* g = gwave + (size_t)(s1 >> 1) * 65536 + (s1 & 1) * 32768;
        unsigned short* lp = &Ks[s1 & 1][wave][0];
#pragma unroll
        for (int c = 0; c < 4; ++c) GL2LDS16(g + c * 512, lp + c * 512);
        WAIT_VMCNT4();
      } else {
        WAIT_VMCNT0();  // nothing issued after the last batch: full drain
      }
      const unsigned short* kw = &Ks[s & 1][wave][ln15 * 64];
#pragma unroll
      for (int jt = 0; jt < 2; ++jt) {
        const unsigned short* kp = kw + jt * 1024;
        const short8 b0 = *(const short8*)(kp + pfrag);
        const short8 b1 = *(const short8*)(kp + (pfrag ^ 32));
        f32x4 cc = {0.0f, 0.0f, 0.0f, 0.0f};
        cc = __builtin_amdgcn_mfma_f32_16x16x32_bf16(a0, b0, cc, 0, 0, 0);
        cc = __builtin_amdgcn_mfma_f32_16x16x32_bf16(a1, b1, cc, 0, 0, 0);
#pragma unroll
        for (int r = 0; r < 4; ++r) {
          const float sv = fminf(cc[r] * QSCALE, SCLAMP);
          const float ev = __builtin_amdgcn_exp2f(sv) * mf[hf][jt][r];
          ef[hf][jt][r] = ev;
          la[r] += ev;
        }
      }
    }
    // wave-local l: DPP butterfly over the 16 key-lanes per q-row
#pragma unroll
    for (int r = 0; r < 4; ++r) la[r] = dpp_red16(la[r]);
    if (ln15 == 0) *(f32x4*)&l_lds[h & 1][wave][rg * 4] = (f32x4){la[0], la[1], la[2], la[3]};
    BARRIER_LGKM();  // ONE raw barrier per head: l exchange only, DMAs stay in flight
    // cross-wave reduce without a second barrier: lane reads wave-ln15's partial
    const f32x4 pw = *(const f32x4*)&l_lds[h & 1][ln15][rg * 4];
#pragma unroll
    for (int r = 0; r < 4; ++r) {
      const float li = __builtin_amdgcn_rcpf(dpp_red16(pw[r]));  // 1/16 folded into store
#pragma unroll
      for (int hf = 0; hf < 2; ++hf)
#pragma unroll
        for (int jt = 0; jt < 2; ++jt) o[hf][jt][r] += ef[hf][jt][r] * li;
    }
  }
  // direct stores: 64 B contiguous per (hf,jt,r) across the 16 key-lanes;
  // 1/16 head-mean folded in here.
#pragma unroll
  for (int hf = 0; hf < 2; ++hf)
#pragma unroll
    for (int jt = 0; jt < 2; ++jt)
#pragma unroll
      for (int r = 0; r < 4; ++r)
        out[((size_t)b * S_ + q0 + rg * 4 + r) * S_ + hf * 512 + wave * 32 + jt * 16 + ln15] =
            o[hf][jt][r] * 0.0625f;
}

extern "C" void kernel_launch(void* const* d_in, const int* in_sizes, int n_in,
                              void* d_out, int out_size, void* d_ws, size_t ws_size,
                              hipStream_t stream) {
  const float* x = (const float*)d_in[0];
  const int* mask = (const int*)d_in[1];
  const float* Wq = (const float*)d_in[2];
  const float* bq = (const float*)d_in[3];
  const float* Wk = (const float*)d_in[4];
  const float* bk = (const float*)d_in[5];
  const float* gq = (const float*)d_in[6];
  const float* bq_n = (const float*)d_in[7];
  const float* gk = (const float*)d_in[8];
  const float* bk_n = (const float*)d_in[9];
  float* out = (float*)d_out;

  char* ws = (char*)d_ws;
  const size_t MB = 1024 * 1024;

  if (ws_size >= 40 * MB) {
    // fused layout (40 MB): P2 bf16 [4096][2048] @0 (16), xbf @16 (8, Kbf aliases),
    // Wt @24 (4), Qbf @28 (8), msym @36 (4)
    unsigned short* P2 = (unsigned short*)ws;
    unsigned short* xbf = (unsigned short*)(ws + 16 * MB);
    unsigned short* Kbf = (unsigned short*)(ws + 16 * MB);   // alias: xbf dead after gemm
    unsigned short* Wt = (unsigned short*)(ws + 24 * MB);
    unsigned short* Qbf = (unsigned short*)(ws + 28 * MB);
    unsigned char* msym = (unsigned char*)(ws + 36 * MB);

    prep_kernel<<<8192, 256, 0, stream>>>(mask, x, Wq, Wk, msym, xbf, Wt);
    gemm_mfma_kernel<<<512, 256, 0, stream>>>(xbf, Wt, P2, 2048);
    ln2_kernel<<<8192, 256, 0, stream>>>(P2, bq, gq, bq_n, bk, gk, bk_n, Qbf, Kbf);
    attn15_kernel<<<256, 1024, 0, stream>>>(Qbf, Kbf, msym, out);
  } else {
    // split layout (32 MB): P bf16 [4096][1024] @0 (8), xbf @8 (8, Kbf aliases),
    // Wt @16 (4), Qbf @20 (8), msym @28 (4)
    unsigned short* P = (unsigned short*)ws;
    unsigned short* xbf = (unsigned short*)(ws + 8 * MB);
    unsigned short* Kbf = (unsigned short*)(ws + 8 * MB);    // alias: xbf dead after 2nd gemm
    unsigned short* Wt = (unsigned short*)(ws + 16 * MB);
    unsigned short* Qbf = (unsigned short*)(ws + 20 * MB);
    unsigned char* msym = (unsigned char*)(ws + 28 * MB);

    prep_kernel<<<8192, 256, 0, stream>>>(mask, x, Wq, Wk, msym, xbf, Wt);
    gemm_mfma_kernel<<<256, 256, 0, stream>>>(xbf, Wt, P, 1024);
    ln_relu_bf_kernel<<<4096, 256, 0, stream>>>(P, 1024, 0, bq, gq, bq_n, Qbf);
    gemm_mfma_kernel<<<256, 256, 0, stream>>>(xbf, Wt + (size_t)1024 * 1024, P, 1024);
    ln_relu_bf_kernel<<<4096, 256, 0, stream>>>(P, 1024, 0, bk, gk, bk_n, Kbf);
    attn15_kernel<<<256, 1024, 0, stream>>>(Qbf, Kbf, msym, out);
  }
}